// Round 11
// baseline (548.533 us; speedup 1.0000x reference)
//
#include <hip/hip_runtime.h>

#define NPTS 500000
#define NVOX 50000
#define NBLK 196   // ceil(NVOX/256)

typedef unsigned short u16;
typedef unsigned int u32;
typedef __attribute__((ext_vector_type(8))) short short8;
typedef __attribute__((ext_vector_type(4))) float floatx4;
typedef __attribute__((ext_vector_type(4))) unsigned int uintx4;
typedef __attribute__((ext_vector_type(2))) unsigned int uintx2;
typedef __attribute__((ext_vector_type(2))) unsigned short us2;

// packed fp32->bf16 RNE (1 instr for 2 values)
__device__ __forceinline__ u32 pkbf(float lo, float hi) {
    u32 r;
    asm("v_cvt_pk_bf16_f32 %0, %1, %2" : "=v"(r) : "v"(lo), "v"(hi));
    return r;
}
__device__ __forceinline__ u16 f2bf(float f) {
    u32 r;
    asm("v_cvt_pk_bf16_f32 %0, %1, %1" : "=v"(r) : "v"(f));
    return (u16)r;
}
// packed u16 max (bf16 values >= 0 compare as u16)
__device__ __forceinline__ u32 pmax(u32 a, u32 b) {
    us2 r = __builtin_elementwise_max(__builtin_bit_cast(us2, a), __builtin_bit_cast(us2, b));
    return __builtin_bit_cast(u32, r);
}

// ---- weight swizzle helper: fp32 (K x N row-major) -> fragment-contiguous bf16 ----
//   Wf[((kk*4+q)*N + n)*8 + j] = W[(kk*32+q*8+j)*N + n]
__device__ __forceinline__ void wt_one(const float* __restrict__ W, u16* __restrict__ Wf,
                                       int N, int t, int KN) {
    if (t >= KN) return;
    int k = t / N, n = t - k * N;
    int kk = k >> 5, q = (k >> 3) & 3, j = k & 7;
    Wf[((size_t)((kk * 4 + q) * N + n) << 3) + j] = f2bf(W[t]);
}

// ---- K0: ALL weight transforms + hcnt zero in ONE launch ----
// blocks [0,256) w3 | [256,512) w4 | [512,576) wv1 | [576,832) wv2 |
// [832,864) wcat | [864,880) watt | [880,1076) hcnt=0
__global__ __launch_bounds__(256) void k_prep(
    const float* __restrict__ w3, u16* __restrict__ w3f,
    const float* __restrict__ w4, u16* __restrict__ w4f,
    const float* __restrict__ wv1, u16* __restrict__ wv1f,
    const float* __restrict__ wv2, u16* __restrict__ wv2f,
    const float* __restrict__ w2x, const float* __restrict__ w2r, u16* __restrict__ wcatf,
    const float* __restrict__ wax, const float* __restrict__ war, u16* __restrict__ wattf,
    int* __restrict__ hcnt)
{
    int b = blockIdx.x, tid = threadIdx.x;
    if (b < 256) {
        wt_one(w3, w3f, 256, b * 256 + tid, 65536);
    } else if (b < 512) {
        wt_one(w4, w4f, 256, (b - 256) * 256 + tid, 65536);
    } else if (b < 576) {
        wt_one(wv1, wv1f, 128, (b - 512) * 256 + tid, 16384);
    } else if (b < 832) {
        wt_one(wv2, wv2f, 256, (b - 576) * 256 + tid, 65536);
    } else if (b < 864) {   // block-diag [[w2x,0],[0,w2r]] (128x64)
        int t = (b - 832) * 256 + tid;
        int k = t >> 6, n = t & 63;
        float v;
        if (k < 64) v = (n < 32) ? w2x[k * 32 + n] : 0.f;
        else        v = (n >= 32) ? w2r[(k - 64) * 32 + (n - 32)] : 0.f;
        int kk = k >> 5, q = (k >> 3) & 3, j = k & 7;
        wcatf[((size_t)((kk * 4 + q) * 64 + n) << 3) + j] = f2bf(v);
    } else if (b < 880) {   // [wax | war] (64x64)
        int t = (b - 864) * 256 + tid;
        int k = t >> 6, n = t & 63;
        float v = (n < 32) ? wax[k * 32 + n] : war[k * 32 + (n - 32)];
        int kk = k >> 5, q = (k >> 3) & 3, j = k & 7;
        wattf[((size_t)((kk * 4 + q) * 64 + n) << 3) + j] = f2bf(v);
    } else {                // zero hcnt
        int i = (b - 880) * 256 + tid;
        if (i < NVOX) hcnt[i] = 0;
    }
}

// ---- CSR build: histogram -> 3-phase parallel scan -> scatter (inps permute + sorted vid) ----
__global__ void k_hist(const int* __restrict__ idx, int* __restrict__ hcnt) {
    int i = blockIdx.x * 256 + threadIdx.x;
    if (i < NPTS) atomicAdd(&hcnt[idx[i]], 1);
}

__global__ __launch_bounds__(256) void k_scan1(const int* __restrict__ hcnt, int* __restrict__ bsum) {
    __shared__ int wsum[4];
    int t = threadIdx.x;
    int i = blockIdx.x * 256 + t;
    int c = (i < NVOX) ? hcnt[i] : 0;
    #pragma unroll
    for (int d = 32; d >= 1; d >>= 1) c += __shfl_xor(c, d, 64);
    if ((t & 63) == 0) wsum[t >> 6] = c;
    __syncthreads();
    if (t == 0) bsum[blockIdx.x] = wsum[0] + wsum[1] + wsum[2] + wsum[3];
}

__global__ __launch_bounds__(256) void k_scan2(const int* __restrict__ bsum, int* __restrict__ boff) {
    __shared__ int wsum[4];
    int t = threadIdx.x, lane = t & 63, w = t >> 6;
    int c = (t < NBLK) ? bsum[t] : 0;
    int v = c;
    #pragma unroll
    for (int d = 1; d < 64; d <<= 1) {
        int o = __shfl_up(v, d, 64);
        if (lane >= d) v += o;
    }
    if (lane == 63) wsum[w] = v;
    __syncthreads();
    int wo = 0;
    #pragma unroll
    for (int k = 0; k < 4; k++) if (k < w) wo += wsum[k];
    if (t < NBLK) boff[t] = wo + v - c;
}

__global__ __launch_bounds__(256) void k_scan3(const int* __restrict__ hcnt, const int* __restrict__ boff,
                                               int* __restrict__ cur) {
    __shared__ int wsum[4];
    int t = threadIdx.x, lane = t & 63, w = t >> 6;
    int i = blockIdx.x * 256 + t;
    int c = (i < NVOX) ? hcnt[i] : 0;
    int v = c;
    #pragma unroll
    for (int d = 1; d < 64; d <<= 1) {
        int o = __shfl_up(v, d, 64);
        if (lane >= d) v += o;
    }
    if (lane == 63) wsum[w] = v;
    __syncthreads();
    int wo = 0;
    #pragma unroll
    for (int k = 0; k < 4; k++) if (k < w) wo += wsum[k];
    if (i < NVOX) cur[i] = boff[blockIdx.x] + wo + v - c;
}

// scatter: permute inp rows into sorted order (random access lives HERE, where
// scattered WRITES don't stall waves; k_pointfeat then reads inps fully coalesced)
__global__ void k_scatter(const int* __restrict__ idx, int* __restrict__ cur,
                          const float* __restrict__ inp,
                          float* __restrict__ inps, int* __restrict__ svid) {
    int i = blockIdx.x * 256 + threadIdx.x;
    if (i < NPTS) {
        int v = idx[i];
        int pos = atomicAdd(&cur[v], 1);
        svid[pos] = v;
        const float2* s = (const float2*)(inp + (size_t)i * 6);
        float2 a = s[0], b = s[1], c = s[2];
        float2* d = (float2*)(inps + (size_t)pos * 6);
        d[0] = a; d[1] = b; d[2] = c;
    }
}

// ---- K1: sorted-order MFMA point encoder + fused pf2 segment-max -> voxmax (fp32) ----
// 512 threads / 8 waves; inps read coalesced; segmax 4x16-row groups on 256 lanes.
__global__ __launch_bounds__(512) void k_pointfeat(
    const float* __restrict__ inps, const int* __restrict__ svid,
    const float* __restrict__ w1x, const float* __restrict__ b1x,
    const float* __restrict__ w1r, const float* __restrict__ b1r,
    const u16* __restrict__ wcatf, const float* __restrict__ b2x, const float* __restrict__ b2r,
    const u16* __restrict__ wattf, const float* __restrict__ bax, const float* __restrict__ bar,
    u16* __restrict__ pf2s, float* __restrict__ voxmax)
{
    __shared__ u16 hbuf[64 * 136];   // h tile (64x128 +8 pad); reused for pf2 out-tile
    __shared__ u16 cbuf[64 * 72];    // comb tile (64x64 +8 pad)
    __shared__ float wl[512];        // w1x(192) b1x(64) w1r(192) b1r(64)
    __shared__ int lvid[64];
    int t = threadIdx.x;
    int i0 = blockIdx.x * 64;
    int mcnt = NPTS - i0; if (mcnt > 64) mcnt = 64;
    {
        float v;
        if (t < 192)      v = w1x[t];
        else if (t < 256) v = b1x[t - 192];
        else if (t < 448) v = w1r[t - 256];
        else              v = b1r[t - 448];
        wl[t] = v;
    }
    if (t < 64) lvid[t] = (t < mcnt) ? svid[i0 + t] : -1;
    __syncthreads();
    {   // layer 1: K=3 on VALU, 8 threads/point each produce 8 h_x + 8 h_r cols
        int m = t >> 3, c = t & 7;
        float x0 = 0, x1 = 0, x2 = 0, r0 = 0, r1 = 0, r2 = 0;
        if (m < mcnt) {
            const float* p = inps + (size_t)(i0 + m) * 6;   // sorted, coalesced
            x0 = p[0]; x1 = p[1]; x2 = p[2]; r0 = p[3]; r1 = p[4]; r2 = p[5];
        }
        u16* hb = &hbuf[m * 136 + c * 8];
        #pragma unroll
        for (int jp = 0; jp < 4; jp++) {
            int c0 = c * 8 + 2 * jp, c1 = c0 + 1;
            float hx0 = fmaxf(wl[192 + c0] + x0 * wl[c0] + x1 * wl[64 + c0] + x2 * wl[128 + c0], 0.f);
            float hx1 = fmaxf(wl[192 + c1] + x0 * wl[c1] + x1 * wl[64 + c1] + x2 * wl[128 + c1], 0.f);
            float hr0 = fmaxf(wl[448 + c0] + r0 * wl[256 + c0] + r1 * wl[320 + c0] + r2 * wl[384 + c0], 0.f);
            float hr1 = fmaxf(wl[448 + c1] + r0 * wl[256 + c1] + r1 * wl[320 + c1] + r2 * wl[384 + c1], 0.f);
            *(u32*)(hb + 2 * jp)      = pkbf(hx0, hx1);
            *(u32*)(hb + 64 + 2 * jp) = pkbf(hr0, hr1);
        }
    }
    __syncthreads();
    int wave = t >> 6, l = t & 63, q = l >> 4, lm = l & 15;
    int g = wave & 3;          // col group: n = g*16+lm
    int h2 = wave >> 2;        // row half: tm in {2h2, 2h2+1}
    int n = g * 16 + lm;
    // GEMM1: comb(64x64) = h(64x128) @ wcat(128x64); wave does 2 of 4 row-tiles
    floatx4 acc[2];
    #pragma unroll
    for (int a = 0; a < 2; a++) acc[a] = (floatx4){0.f, 0.f, 0.f, 0.f};
    #pragma unroll
    for (int kk = 0; kk < 4; kk++) {
        short8 bfrag = *(const short8*)&wcatf[(size_t)((kk * 4 + q) * 64 + n) << 3];
        #pragma unroll
        for (int ti = 0; ti < 2; ti++) {
            int tm = h2 * 2 + ti;
            short8 afrag = *(const short8*)&hbuf[(tm * 16 + lm) * 136 + kk * 32 + q * 8];
            acc[ti] = __builtin_amdgcn_mfma_f32_16x16x32_bf16(afrag, bfrag, acc[ti], 0, 0, 0);
        }
    }
    float bv = (n < 32) ? b2x[n] : b2r[n - 32];
    float comb_keep[2][4];
    #pragma unroll
    for (int ti = 0; ti < 2; ti++)
        #pragma unroll
        for (int r = 0; r < 4; r++) {
            int tm = h2 * 2 + ti;
            float v = fmaxf(acc[ti][r] + bv, 0.f);
            comb_keep[ti][r] = v;
            int m = tm * 16 + q * 4 + r;     // C/D: row = quad*4+reg, col = lane&15
            cbuf[m * 72 + n] = f2bf(v);
        }
    __syncthreads();
    // GEMM2: att(64x64) = comb @ watt; same C-layout as comb -> register-local gating
    floatx4 acc2[2];
    #pragma unroll
    for (int a = 0; a < 2; a++) acc2[a] = (floatx4){0.f, 0.f, 0.f, 0.f};
    #pragma unroll
    for (int kk = 0; kk < 2; kk++) {
        short8 bfrag = *(const short8*)&wattf[(size_t)((kk * 4 + q) * 64 + n) << 3];
        #pragma unroll
        for (int ti = 0; ti < 2; ti++) {
            int tm = h2 * 2 + ti;
            short8 afrag = *(const short8*)&cbuf[(tm * 16 + lm) * 72 + kk * 32 + q * 8];
            acc2[ti] = __builtin_amdgcn_mfma_f32_16x16x32_bf16(afrag, bfrag, acc2[ti], 0, 0, 0);
        }
    }
    float bv2 = (n < 32) ? bax[n] : bar[n - 32];
    int pp = (n < 32) ? n : 32 + n;   // pf2 col of plain value; gated at pp+32
    #pragma unroll
    for (int ti = 0; ti < 2; ti++)
        #pragma unroll
        for (int r = 0; r < 4; r++) {
            int tm = h2 * 2 + ti;
            float att = acc2[ti][r] + bv2;
            float sg = 1.f / (1.f + __expf(-att));
            float plain = comb_keep[ti][r];
            float gated = plain * sg;
            int m = tm * 16 + q * 4 + r;
            hbuf[m * 136 + pp] = f2bf(plain);
            hbuf[m * 136 + pp + 32] = f2bf(gated);
        }
    __syncthreads();
    {   // coalesced pf2s store (sorted rows): 8 threads/row x 16B
        int row = t >> 3, seg = t & 7;
        if (row < mcnt) {
            const u16* src = &hbuf[row * 136 + seg * 16];
            u16* dst = pf2s + (size_t)(i0 + row) * 128 + seg * 16;
            *(uintx4*)dst = *(const uintx4*)src;
        }
    }
    if (t < 256) {   // fused segment-max: 4x16-row groups, 256 lanes
        int c2 = t & 63;           // u32 col (u16 cols 2c2, 2c2+1) of 128
        int h = t >> 6;            // row quarter (16 rows)
        int r0 = h * 16;
        int r1 = r0 + 16; if (r1 > mcnt) r1 = mcnt;
        u32 mm = 0;
        int pvid = -1;
        for (int r = r0; r < r1; r++) {
            int vid = lvid[r];
            if (vid != pvid) {
                if (pvid >= 0) {
                    int* addr = (int*)(voxmax + (size_t)pvid * 128 + 2 * c2);
                    if (mm << 16) atomicMax(addr, (int)(mm << 16));
                    if (mm & 0xffff0000u) atomicMax(addr + 1, (int)(mm & 0xffff0000u));
                }
                pvid = vid; mm = 0;
            }
            u32 u = *(const u32*)&hbuf[r * 136 + 2 * c2];
            mm = pmax(mm, u);
        }
        if (pvid >= 0) {
            int* addr = (int*)(voxmax + (size_t)pvid * 128 + 2 * c2);
            if (mm << 16) atomicMax(addr, (int)(mm << 16));
            if (mm & 0xffff0000u) atomicMax(addr + 1, (int)(mm & 0xffff0000u));
        }
    }
}

// ---- generic MFMA GEMM: out = relu(A @ W + bias); A fp32 or bf16; W pre-swizzled bf16 ----
template<int K, int N, bool ABF16, bool OUT_BF16>
__global__ __launch_bounds__(256) void k_gemm_relu(
    const void* __restrict__ Ap, const u16* __restrict__ Wf,
    const float* __restrict__ bias, void* __restrict__ outp, int M)
{
    constexpr int STRIDE = K + 8;
    constexpr int TN = N / 64;
    constexpr int KSTEPS = K / 32;
    constexpr int CW = K / 4;
    __shared__ u16 lds[64 * STRIDE];
    int i0 = blockIdx.x * 64;
    int mcnt = M - i0; if (mcnt > 64) mcnt = 64;
    int t = threadIdx.x;
    {
        int row = t >> 2, cseg = t & 3;
        u16* dst = &lds[row * STRIDE + cseg * CW];
        if (row < mcnt) {
            if (ABF16) {
                const u16* src = (const u16*)Ap + (size_t)(i0 + row) * K + cseg * CW;
                #pragma unroll
                for (int c = 0; c < CW / 8; c++)
                    *(uintx4*)(dst + c * 8) = *(const uintx4*)(src + c * 8);
            } else {
                const float* src = (const float*)Ap + (size_t)(i0 + row) * K + cseg * CW;
                #pragma unroll
                for (int c = 0; c < CW / 8; c++) {
                    float4 v0 = *(const float4*)(src + c * 8);
                    float4 v1 = *(const float4*)(src + c * 8 + 4);
                    uintx4 rr = (uintx4){ pkbf(v0.x, v0.y), pkbf(v0.z, v0.w),
                                          pkbf(v1.x, v1.y), pkbf(v1.z, v1.w) };
                    *(uintx4*)(dst + c * 8) = rr;
                }
            }
        } else {
            short8 z = {0, 0, 0, 0, 0, 0, 0, 0};
            #pragma unroll
            for (int c = 0; c < CW / 8; c++) *(short8*)(dst + c * 8) = z;
        }
    }
    __syncthreads();
    int wave = t >> 6, l = t & 63;
    int q = l >> 4, lm = l & 15;
    int wn0 = wave * (N / 4);
    floatx4 acc[4][TN];
    #pragma unroll
    for (int a = 0; a < 4; a++)
        #pragma unroll
        for (int b = 0; b < TN; b++) acc[a][b] = (floatx4){0.f, 0.f, 0.f, 0.f};
    #pragma unroll
    for (int kk = 0; kk < KSTEPS; kk++) {
        short8 afrag[4], bfrag[TN];
        #pragma unroll
        for (int tm = 0; tm < 4; tm++)
            afrag[tm] = *(const short8*)&lds[(tm * 16 + lm) * STRIDE + kk * 32 + q * 8];
        #pragma unroll
        for (int tn = 0; tn < TN; tn++)
            bfrag[tn] = *(const short8*)&Wf[(size_t)((kk * 4 + q) * N + wn0 + tn * 16 + lm) * 8];
        #pragma unroll
        for (int tm = 0; tm < 4; tm++)
            #pragma unroll
            for (int tn = 0; tn < TN; tn++)
                acc[tm][tn] = __builtin_amdgcn_mfma_f32_16x16x32_bf16(afrag[tm], bfrag[tn], acc[tm][tn], 0, 0, 0);
    }
    #pragma unroll
    for (int tm = 0; tm < 4; tm++)
        #pragma unroll
        for (int tn = 0; tn < TN; tn++) {
            int n = wn0 + tn * 16 + lm;
            float bv = bias[n];
            #pragma unroll
            for (int r = 0; r < 4; r++) {
                int m = tm * 16 + q * 4 + r;
                if (m < mcnt) {
                    float v = fmaxf(acc[tm][tn][r] + bv, 0.f);
                    if (OUT_BF16) ((u16*)outp)[(size_t)(i0 + m) * N + n] = f2bf(v);
                    else          ((float*)outp)[(size_t)(i0 + m) * N + n] = v;
                }
            }
        }
}

// ---- K3: sorted fused point MLP + in-LDS segmented max -> vox2 ----
// v10: 64-row tile (R4 size), 8 waves = 4 col-groups (64-wide, tm 0..3) x 2 row-halves
// (tn = rh*2+ti). Per kk per wave: 2 bfrag LDS reads + 4 wfrag L2 reads -> 8 MFMA =
// 4 MFMA/LDS-read (vs R4's 2). GEMM-phase ds_reads halve (512->256 wave-instrs/block);
// R10 pipe model says LDS (~98us of 177) is the largest consumer. acc[4][2]=32 regs,
// wfrag[4]=16 -> peak ~80 VGPR. Weights read 2x/block (L2-resident, ~free).
__global__ __launch_bounds__(512) void k_pointmlp(
    const u16* __restrict__ voxf, const u16* __restrict__ pf2s, const int* __restrict__ svid,
    const u16* __restrict__ w3f, const float* __restrict__ b3,
    const u16* __restrict__ w4f, const float* __restrict__ b4,
    float* __restrict__ vox2)
{
    constexpr int STRIDE = 264;
    __shared__ u16 lds[64 * STRIDE];
    __shared__ int lvid[64];
    __shared__ float bl[512];   // b3(256) | b4(256)
    int i0 = blockIdx.x * 64;
    int mcnt = NPTS - i0; if (mcnt > 64) mcnt = 64;
    int t = threadIdx.x;
    if (t < 64) lvid[t] = (t < mcnt) ? svid[i0 + t] : -1;
    bl[t] = (t < 256) ? b3[t] : b4[t - 256];
    {   // stage: 8 threads/row; thread j covers u16 cols [j*16,+16) of each 128-col half
        int row = t >> 3, j = t & 7;
        int sv = (row < mcnt) ? svid[i0 + row] : 0;
        u16* dstb = &lds[row * STRIDE + j * 16];
        uintx4 a0 = (uintx4){0,0,0,0}, a1 = a0, b0 = a0, b1 = a0;
        if (row < mcnt) {
            const u16* s0 = voxf + (size_t)sv * 128 + j * 16;            // pg half (sorted: locality)
            const u16* s1 = pf2s + (size_t)(i0 + row) * 128 + j * 16;    // pf2 half (coalesced)
            a0 = *(const uintx4*)s0; a1 = *(const uintx4*)(s0 + 8);
            b0 = *(const uintx4*)s1; b1 = *(const uintx4*)(s1 + 8);
        }
        *(uintx4*)(dstb) = a0;
        *(uintx4*)(dstb + 8) = a1;
        *(uintx4*)(dstb + 128) = b0;
        *(uintx4*)(dstb + 136) = b1;
    }
    __syncthreads();
    int wave = t >> 6, l = t & 63;
    int q = l >> 4, lm = l & 15;
    int cg = wave & 3;           // col group: 64-wide stripe
    int rh = wave >> 2;          // row half: tn = rh*2 + ti
    int wm0 = cg * 64;
    floatx4 acc[4][2];
    #pragma unroll
    for (int a = 0; a < 4; a++)
        #pragma unroll
        for (int b = 0; b < 2; b++) acc[a][b] = (floatx4){0.f, 0.f, 0.f, 0.f};
    // GEMM1: D = W3^T @ Act^T
    #pragma unroll
    for (int kk = 0; kk < 8; kk++) {
        short8 wfrag[4], bfrag[2];
        #pragma unroll
        for (int tm = 0; tm < 4; tm++)
            wfrag[tm] = *(const short8*)&w3f[(size_t)((kk * 4 + q) * 256 + wm0 + tm * 16 + lm) * 8];
        #pragma unroll
        for (int ti = 0; ti < 2; ti++)
            bfrag[ti] = *(const short8*)&lds[((rh * 2 + ti) * 16 + lm) * STRIDE + kk * 32 + q * 8];
        #pragma unroll
        for (int tm = 0; tm < 4; tm++)
            #pragma unroll
            for (int ti = 0; ti < 2; ti++)
                acc[tm][ti] = __builtin_amdgcn_mfma_f32_16x16x32_bf16(wfrag[tm], bfrag[ti], acc[tm][ti], 0, 0, 0);
    }
    __syncthreads();
    // H = relu(acc + b3) -> LDS row-major, packed b64 (4 consecutive cols per frag)
    #pragma unroll
    for (int tm = 0; tm < 4; tm++) {
        float4 bq = *(const float4*)&bl[wm0 + tm * 16 + 4 * q];
        #pragma unroll
        for (int ti = 0; ti < 2; ti++) {
            u32 lo = pkbf(fmaxf(acc[tm][ti][0] + bq.x, 0.f), fmaxf(acc[tm][ti][1] + bq.y, 0.f));
            u32 hi = pkbf(fmaxf(acc[tm][ti][2] + bq.z, 0.f), fmaxf(acc[tm][ti][3] + bq.w, 0.f));
            *(uintx2*)&lds[((rh * 2 + ti) * 16 + lm) * STRIDE + wm0 + tm * 16 + 4 * q] = (uintx2){lo, hi};
        }
    }
    __syncthreads();
    floatx4 acc2[4][2];
    #pragma unroll
    for (int a = 0; a < 4; a++)
        #pragma unroll
        for (int b = 0; b < 2; b++) acc2[a][b] = (floatx4){0.f, 0.f, 0.f, 0.f};
    // GEMM2: D = W4^T @ H^T
    #pragma unroll
    for (int kk = 0; kk < 8; kk++) {
        short8 wfrag[4], bfrag[2];
        #pragma unroll
        for (int tm = 0; tm < 4; tm++)
            wfrag[tm] = *(const short8*)&w4f[(size_t)((kk * 4 + q) * 256 + wm0 + tm * 16 + lm) * 8];
        #pragma unroll
        for (int ti = 0; ti < 2; ti++)
            bfrag[ti] = *(const short8*)&lds[((rh * 2 + ti) * 16 + lm) * STRIDE + kk * 32 + q * 8];
        #pragma unroll
        for (int tm = 0; tm < 4; tm++)
            #pragma unroll
            for (int ti = 0; ti < 2; ti++)
                acc2[tm][ti] = __builtin_amdgcn_mfma_f32_16x16x32_bf16(wfrag[tm], bfrag[ti], acc2[tm][ti], 0, 0, 0);
    }
    __syncthreads();   // all waves done reading H before overwrite
    // pf5 = relu(acc2 + b4) -> LDS row-major, packed b64
    #pragma unroll
    for (int tm = 0; tm < 4; tm++) {
        float4 bq = *(const float4*)&bl[256 + wm0 + tm * 16 + 4 * q];
        #pragma unroll
        for (int ti = 0; ti < 2; ti++) {
            u32 lo = pkbf(fmaxf(acc2[tm][ti][0] + bq.x, 0.f), fmaxf(acc2[tm][ti][1] + bq.y, 0.f));
            u32 hi = pkbf(fmaxf(acc2[tm][ti][2] + bq.z, 0.f), fmaxf(acc2[tm][ti][3] + bq.w, 0.f));
            *(uintx2*)&lds[((rh * 2 + ti) * 16 + lm) * STRIDE + wm0 + tm * 16 + 4 * q] = (uintx2){lo, hi};
        }
    }
    __syncthreads();
    // segmented max over sorted vid runs: thread owns u32 col x 16-row quarter
    {
        int c2 = t & 127;          // u32 column (u16 cols 2c2, 2c2+1)
        int h = t >> 7;            // row quarter (16 rows)
        int r0 = h * 16;
        int r1 = r0 + 16; if (r1 > mcnt) r1 = mcnt;
        u32 mm = 0;
        int pvid = -1;
        for (int r = r0; r < r1; r++) {
            int vid = lvid[r];
            if (vid != pvid) {
                if (pvid >= 0) {
                    int* addr = (int*)(vox2 + (size_t)pvid * 256 + 2 * c2);
                    if (mm << 16) atomicMax(addr, (int)(mm << 16));
                    if (mm & 0xffff0000u) atomicMax(addr + 1, (int)(mm & 0xffff0000u));
                }
                pvid = vid; mm = 0;
            }
            u32 u = *(const u32*)&lds[r * STRIDE + 2 * c2];
            mm = pmax(mm, u);
        }
        if (pvid >= 0) {
            int* addr = (int*)(vox2 + (size_t)pvid * 256 + 2 * c2);
            if (mm << 16) atomicMax(addr, (int)(mm << 16));
            if (mm & 0xffff0000u) atomicMax(addr + 1, (int)(mm & 0xffff0000u));
        }
    }
}

extern "C" void kernel_launch(void* const* d_in, const int* in_sizes, int n_in,
                              void* d_out, int out_size, void* d_ws, size_t ws_size,
                              hipStream_t stream) {
    const float* inp = (const float*)d_in[0];
    const int*   idx = (const int*)d_in[1];
    const float* w1x = (const float*)d_in[3];  const float* b1x = (const float*)d_in[4];
    const float* w2x = (const float*)d_in[5];  const float* b2x = (const float*)d_in[6];
    const float* w1r = (const float*)d_in[7];  const float* b1r = (const float*)d_in[8];
    const float* w2r = (const float*)d_in[9];  const float* b2r = (const float*)d_in[10];
    const float* wax = (const float*)d_in[11]; const float* bax = (const float*)d_in[12];
    const float* war = (const float*)d_in[13]; const float* bar = (const float*)d_in[14];
    const float* wv1 = (const float*)d_in[15]; const float* bv1 = (const float*)d_in[16];
    const float* w3  = (const float*)d_in[17]; const float* b3  = (const float*)d_in[18];
    const float* w4  = (const float*)d_in[19]; const float* b4  = (const float*)d_in[20];
    const float* wv2 = (const float*)d_in[21]; const float* bv2 = (const float*)d_in[22];
    float* out = (float*)d_out;

    char* ws = (char*)d_ws;
    u16*   pf2s   = (u16*)ws;   ws += (size_t)NPTS * 128 * sizeof(u16);   // 128 MB (sorted rows)
    float* voxmax = (float*)ws; ws += (size_t)NVOX * 128 * sizeof(float); // 25.6 MB
    u16*   voxf   = (u16*)ws;   ws += (size_t)NVOX * 128 * sizeof(u16);   // 12.8 MB
    float* vox2   = (float*)ws; ws += (size_t)NVOX * 256 * sizeof(float); // 51.2 MB
    float* inps   = (float*)ws; ws += (size_t)NPTS * 6 * sizeof(float);   // 12 MB (sorted inp)
    u16*   w3f    = (u16*)ws;   ws += 65536 * sizeof(u16);
    u16*   w4f    = (u16*)ws;   ws += 65536 * sizeof(u16);
    u16*   wv1f   = (u16*)ws;   ws += 16384 * sizeof(u16);
    u16*   wv2f   = (u16*)ws;   ws += 65536 * sizeof(u16);
    u16*   wcatf  = (u16*)ws;   ws += 8192 * sizeof(u16);
    u16*   wattf  = (u16*)ws;   ws += 4096 * sizeof(u16);
    int*   hcnt   = (int*)ws;   ws += (size_t)NVOX * sizeof(int);
    int*   cur    = (int*)ws;   ws += (size_t)NVOX * sizeof(int);
    int*   bsum   = (int*)ws;   ws += (size_t)NBLK * sizeof(int);
    int*   boff   = (int*)ws;   ws += (size_t)NBLK * sizeof(int);
    int*   svid   = (int*)ws;   ws += (size_t)NPTS * sizeof(int);

    hipMemsetAsync(voxmax, 0, (size_t)NVOX * 128 * sizeof(float), stream);
    hipMemsetAsync(vox2, 0, (size_t)NVOX * 256 * sizeof(float), stream);

    k_prep<<<1076, 256, 0, stream>>>(w3, w3f, w4, w4f, wv1, wv1f, wv2, wv2f,
                                     w2x, w2r, wcatf, wax, war, wattf, hcnt);

    k_hist<<<(NPTS + 255) / 256, 256, 0, stream>>>(idx, hcnt);
    k_scan1<<<NBLK, 256, 0, stream>>>(hcnt, bsum);
    k_scan2<<<1, 256, 0, stream>>>(bsum, boff);
    k_scan3<<<NBLK, 256, 0, stream>>>(hcnt, boff, cur);
    k_scatter<<<(NPTS + 255) / 256, 256, 0, stream>>>(idx, cur, inp, inps, svid);

    k_pointfeat<<<(NPTS + 63) / 64, 512, 0, stream>>>(
        inps, svid, w1x, b1x, w1r, b1r, wcatf, b2x, b2r, wattf, bax, bar, pf2s, voxmax);

    k_gemm_relu<128, 128, false, true><<<(NVOX + 63) / 64, 256, 0, stream>>>(
        (const void*)voxmax, wv1f, bv1, (void*)voxf, NVOX);

    k_pointmlp<<<(NPTS + 63) / 64, 512, 0, stream>>>(
        voxf, pf2s, svid, w3f, b3, w4f, b4, vox2);

    k_gemm_relu<256, 256, false, false><<<(NVOX + 63) / 64, 256, 0, stream>>>(
        (const void*)vox2, wv2f, bv2, (void*)out, NVOX);
}

// Round 12
// 481.016 us; speedup vs baseline: 1.1404x; 1.1404x over previous
//
#include <hip/hip_runtime.h>

#define NPTS 500000
#define NVOX 50000
#define NBLK 196   // ceil(NVOX/256)

typedef unsigned short u16;
typedef unsigned int u32;
typedef __attribute__((ext_vector_type(8))) short short8;
typedef __attribute__((ext_vector_type(4))) float floatx4;
typedef __attribute__((ext_vector_type(4))) unsigned int uintx4;
typedef __attribute__((ext_vector_type(2))) unsigned int uintx2;
typedef __attribute__((ext_vector_type(2))) unsigned short us2;

// packed fp32->bf16 RNE (1 instr for 2 values)
__device__ __forceinline__ u32 pkbf(float lo, float hi) {
    u32 r;
    asm("v_cvt_pk_bf16_f32 %0, %1, %2" : "=v"(r) : "v"(lo), "v"(hi));
    return r;
}
__device__ __forceinline__ u16 f2bf(float f) {
    u32 r;
    asm("v_cvt_pk_bf16_f32 %0, %1, %1" : "=v"(r) : "v"(f));
    return (u16)r;
}
// packed u16 max (bf16 values >= 0 compare as u16)
__device__ __forceinline__ u32 pmax(u32 a, u32 b) {
    us2 r = __builtin_elementwise_max(__builtin_bit_cast(us2, a), __builtin_bit_cast(us2, b));
    return __builtin_bit_cast(u32, r);
}

// ---- weight swizzle helper: fp32 (K x N row-major) -> fragment-contiguous bf16 ----
//   Wf[((kk*4+q)*N + n)*8 + j] = W[(kk*32+q*8+j)*N + n]
__device__ __forceinline__ void wt_one(const float* __restrict__ W, u16* __restrict__ Wf,
                                       int N, int t, int KN) {
    if (t >= KN) return;
    int k = t / N, n = t - k * N;
    int kk = k >> 5, q = (k >> 3) & 3, j = k & 7;
    Wf[((size_t)((kk * 4 + q) * N + n) << 3) + j] = f2bf(W[t]);
}

// ---- K0: ALL weight transforms + hcnt zero in ONE launch ----
// blocks [0,256) w3 | [256,512) w4 | [512,576) wv1 | [576,832) wv2 |
// [832,864) wcat | [864,880) watt | [880,1076) hcnt=0
__global__ __launch_bounds__(256) void k_prep(
    const float* __restrict__ w3, u16* __restrict__ w3f,
    const float* __restrict__ w4, u16* __restrict__ w4f,
    const float* __restrict__ wv1, u16* __restrict__ wv1f,
    const float* __restrict__ wv2, u16* __restrict__ wv2f,
    const float* __restrict__ w2x, const float* __restrict__ w2r, u16* __restrict__ wcatf,
    const float* __restrict__ wax, const float* __restrict__ war, u16* __restrict__ wattf,
    int* __restrict__ hcnt)
{
    int b = blockIdx.x, tid = threadIdx.x;
    if (b < 256) {
        wt_one(w3, w3f, 256, b * 256 + tid, 65536);
    } else if (b < 512) {
        wt_one(w4, w4f, 256, (b - 256) * 256 + tid, 65536);
    } else if (b < 576) {
        wt_one(wv1, wv1f, 128, (b - 512) * 256 + tid, 16384);
    } else if (b < 832) {
        wt_one(wv2, wv2f, 256, (b - 576) * 256 + tid, 65536);
    } else if (b < 864) {   // block-diag [[w2x,0],[0,w2r]] (128x64)
        int t = (b - 832) * 256 + tid;
        int k = t >> 6, n = t & 63;
        float v;
        if (k < 64) v = (n < 32) ? w2x[k * 32 + n] : 0.f;
        else        v = (n >= 32) ? w2r[(k - 64) * 32 + (n - 32)] : 0.f;
        int kk = k >> 5, q = (k >> 3) & 3, j = k & 7;
        wcatf[((size_t)((kk * 4 + q) * 64 + n) << 3) + j] = f2bf(v);
    } else if (b < 880) {   // [wax | war] (64x64)
        int t = (b - 864) * 256 + tid;
        int k = t >> 6, n = t & 63;
        float v = (n < 32) ? wax[k * 32 + n] : war[k * 32 + (n - 32)];
        int kk = k >> 5, q = (k >> 3) & 3, j = k & 7;
        wattf[((size_t)((kk * 4 + q) * 64 + n) << 3) + j] = f2bf(v);
    } else {                // zero hcnt
        int i = (b - 880) * 256 + tid;
        if (i < NVOX) hcnt[i] = 0;
    }
}

// ---- CSR build: histogram -> 3-phase parallel scan -> scatter (inps permute + sorted vid) ----
__global__ void k_hist(const int* __restrict__ idx, int* __restrict__ hcnt) {
    int i = blockIdx.x * 256 + threadIdx.x;
    if (i < NPTS) atomicAdd(&hcnt[idx[i]], 1);
}

__global__ __launch_bounds__(256) void k_scan1(const int* __restrict__ hcnt, int* __restrict__ bsum) {
    __shared__ int wsum[4];
    int t = threadIdx.x;
    int i = blockIdx.x * 256 + t;
    int c = (i < NVOX) ? hcnt[i] : 0;
    #pragma unroll
    for (int d = 32; d >= 1; d >>= 1) c += __shfl_xor(c, d, 64);
    if ((t & 63) == 0) wsum[t >> 6] = c;
    __syncthreads();
    if (t == 0) bsum[blockIdx.x] = wsum[0] + wsum[1] + wsum[2] + wsum[3];
}

__global__ __launch_bounds__(256) void k_scan2(const int* __restrict__ bsum, int* __restrict__ boff) {
    __shared__ int wsum[4];
    int t = threadIdx.x, lane = t & 63, w = t >> 6;
    int c = (t < NBLK) ? bsum[t] : 0;
    int v = c;
    #pragma unroll
    for (int d = 1; d < 64; d <<= 1) {
        int o = __shfl_up(v, d, 64);
        if (lane >= d) v += o;
    }
    if (lane == 63) wsum[w] = v;
    __syncthreads();
    int wo = 0;
    #pragma unroll
    for (int k = 0; k < 4; k++) if (k < w) wo += wsum[k];
    if (t < NBLK) boff[t] = wo + v - c;
}

__global__ __launch_bounds__(256) void k_scan3(const int* __restrict__ hcnt, const int* __restrict__ boff,
                                               int* __restrict__ cur) {
    __shared__ int wsum[4];
    int t = threadIdx.x, lane = t & 63, w = t >> 6;
    int i = blockIdx.x * 256 + t;
    int c = (i < NVOX) ? hcnt[i] : 0;
    int v = c;
    #pragma unroll
    for (int d = 1; d < 64; d <<= 1) {
        int o = __shfl_up(v, d, 64);
        if (lane >= d) v += o;
    }
    if (lane == 63) wsum[w] = v;
    __syncthreads();
    int wo = 0;
    #pragma unroll
    for (int k = 0; k < 4; k++) if (k < w) wo += wsum[k];
    if (i < NVOX) cur[i] = boff[blockIdx.x] + wo + v - c;
}

// scatter: permute inp rows into sorted order (random access lives HERE, where
// scattered WRITES don't stall waves; k_pointfeat then reads inps fully coalesced)
__global__ void k_scatter(const int* __restrict__ idx, int* __restrict__ cur,
                          const float* __restrict__ inp,
                          float* __restrict__ inps, int* __restrict__ svid) {
    int i = blockIdx.x * 256 + threadIdx.x;
    if (i < NPTS) {
        int v = idx[i];
        int pos = atomicAdd(&cur[v], 1);
        svid[pos] = v;
        const float2* s = (const float2*)(inp + (size_t)i * 6);
        float2 a = s[0], b = s[1], c = s[2];
        float2* d = (float2*)(inps + (size_t)pos * 6);
        d[0] = a; d[1] = b; d[2] = c;
    }
}

// ---- K1: sorted-order MFMA point encoder + fused pf2 segment-max -> voxmax (fp32) ----
// 512 threads / 8 waves; inps read coalesced; segmax 4x16-row groups on 256 lanes.
__global__ __launch_bounds__(512) void k_pointfeat(
    const float* __restrict__ inps, const int* __restrict__ svid,
    const float* __restrict__ w1x, const float* __restrict__ b1x,
    const float* __restrict__ w1r, const float* __restrict__ b1r,
    const u16* __restrict__ wcatf, const float* __restrict__ b2x, const float* __restrict__ b2r,
    const u16* __restrict__ wattf, const float* __restrict__ bax, const float* __restrict__ bar,
    u16* __restrict__ pf2s, float* __restrict__ voxmax)
{
    __shared__ u16 hbuf[64 * 136];   // h tile (64x128 +8 pad); reused for pf2 out-tile
    __shared__ u16 cbuf[64 * 72];    // comb tile (64x64 +8 pad)
    __shared__ float wl[512];        // w1x(192) b1x(64) w1r(192) b1r(64)
    __shared__ int lvid[64];
    int t = threadIdx.x;
    int i0 = blockIdx.x * 64;
    int mcnt = NPTS - i0; if (mcnt > 64) mcnt = 64;
    {
        float v;
        if (t < 192)      v = w1x[t];
        else if (t < 256) v = b1x[t - 192];
        else if (t < 448) v = w1r[t - 256];
        else              v = b1r[t - 448];
        wl[t] = v;
    }
    if (t < 64) lvid[t] = (t < mcnt) ? svid[i0 + t] : -1;
    __syncthreads();
    {   // layer 1: K=3 on VALU, 8 threads/point each produce 8 h_x + 8 h_r cols
        int m = t >> 3, c = t & 7;
        float x0 = 0, x1 = 0, x2 = 0, r0 = 0, r1 = 0, r2 = 0;
        if (m < mcnt) {
            const float* p = inps + (size_t)(i0 + m) * 6;   // sorted, coalesced
            x0 = p[0]; x1 = p[1]; x2 = p[2]; r0 = p[3]; r1 = p[4]; r2 = p[5];
        }
        u16* hb = &hbuf[m * 136 + c * 8];
        #pragma unroll
        for (int jp = 0; jp < 4; jp++) {
            int c0 = c * 8 + 2 * jp, c1 = c0 + 1;
            float hx0 = fmaxf(wl[192 + c0] + x0 * wl[c0] + x1 * wl[64 + c0] + x2 * wl[128 + c0], 0.f);
            float hx1 = fmaxf(wl[192 + c1] + x0 * wl[c1] + x1 * wl[64 + c1] + x2 * wl[128 + c1], 0.f);
            float hr0 = fmaxf(wl[448 + c0] + r0 * wl[256 + c0] + r1 * wl[320 + c0] + r2 * wl[384 + c0], 0.f);
            float hr1 = fmaxf(wl[448 + c1] + r0 * wl[256 + c1] + r1 * wl[320 + c1] + r2 * wl[384 + c1], 0.f);
            *(u32*)(hb + 2 * jp)      = pkbf(hx0, hx1);
            *(u32*)(hb + 64 + 2 * jp) = pkbf(hr0, hr1);
        }
    }
    __syncthreads();
    int wave = t >> 6, l = t & 63, q = l >> 4, lm = l & 15;
    int g = wave & 3;          // col group: n = g*16+lm
    int h2 = wave >> 2;        // row half: tm in {2h2, 2h2+1}
    int n = g * 16 + lm;
    // GEMM1: comb(64x64) = h(64x128) @ wcat(128x64); wave does 2 of 4 row-tiles
    floatx4 acc[2];
    #pragma unroll
    for (int a = 0; a < 2; a++) acc[a] = (floatx4){0.f, 0.f, 0.f, 0.f};
    #pragma unroll
    for (int kk = 0; kk < 4; kk++) {
        short8 bfrag = *(const short8*)&wcatf[(size_t)((kk * 4 + q) * 64 + n) << 3];
        #pragma unroll
        for (int ti = 0; ti < 2; ti++) {
            int tm = h2 * 2 + ti;
            short8 afrag = *(const short8*)&hbuf[(tm * 16 + lm) * 136 + kk * 32 + q * 8];
            acc[ti] = __builtin_amdgcn_mfma_f32_16x16x32_bf16(afrag, bfrag, acc[ti], 0, 0, 0);
        }
    }
    float bv = (n < 32) ? b2x[n] : b2r[n - 32];
    float comb_keep[2][4];
    #pragma unroll
    for (int ti = 0; ti < 2; ti++)
        #pragma unroll
        for (int r = 0; r < 4; r++) {
            int tm = h2 * 2 + ti;
            float v = fmaxf(acc[ti][r] + bv, 0.f);
            comb_keep[ti][r] = v;
            int m = tm * 16 + q * 4 + r;     // C/D: row = quad*4+reg, col = lane&15
            cbuf[m * 72 + n] = f2bf(v);
        }
    __syncthreads();
    // GEMM2: att(64x64) = comb @ watt; same C-layout as comb -> register-local gating
    floatx4 acc2[2];
    #pragma unroll
    for (int a = 0; a < 2; a++) acc2[a] = (floatx4){0.f, 0.f, 0.f, 0.f};
    #pragma unroll
    for (int kk = 0; kk < 2; kk++) {
        short8 bfrag = *(const short8*)&wattf[(size_t)((kk * 4 + q) * 64 + n) << 3];
        #pragma unroll
        for (int ti = 0; ti < 2; ti++) {
            int tm = h2 * 2 + ti;
            short8 afrag = *(const short8*)&cbuf[(tm * 16 + lm) * 72 + kk * 32 + q * 8];
            acc2[ti] = __builtin_amdgcn_mfma_f32_16x16x32_bf16(afrag, bfrag, acc2[ti], 0, 0, 0);
        }
    }
    float bv2 = (n < 32) ? bax[n] : bar[n - 32];
    int pp = (n < 32) ? n : 32 + n;   // pf2 col of plain value; gated at pp+32
    #pragma unroll
    for (int ti = 0; ti < 2; ti++)
        #pragma unroll
        for (int r = 0; r < 4; r++) {
            int tm = h2 * 2 + ti;
            float att = acc2[ti][r] + bv2;
            float sg = 1.f / (1.f + __expf(-att));
            float plain = comb_keep[ti][r];
            float gated = plain * sg;
            int m = tm * 16 + q * 4 + r;
            hbuf[m * 136 + pp] = f2bf(plain);
            hbuf[m * 136 + pp + 32] = f2bf(gated);
        }
    __syncthreads();
    {   // coalesced pf2s store (sorted rows): 8 threads/row x 16B
        int row = t >> 3, seg = t & 7;
        if (row < mcnt) {
            const u16* src = &hbuf[row * 136 + seg * 16];
            u16* dst = pf2s + (size_t)(i0 + row) * 128 + seg * 16;
            *(uintx4*)dst = *(const uintx4*)src;
        }
    }
    if (t < 256) {   // fused segment-max: 4x16-row groups, 256 lanes
        int c2 = t & 63;           // u32 col (u16 cols 2c2, 2c2+1) of 128
        int h = t >> 6;            // row quarter (16 rows)
        int r0 = h * 16;
        int r1 = r0 + 16; if (r1 > mcnt) r1 = mcnt;
        u32 mm = 0;
        int pvid = -1;
        for (int r = r0; r < r1; r++) {
            int vid = lvid[r];
            if (vid != pvid) {
                if (pvid >= 0) {
                    int* addr = (int*)(voxmax + (size_t)pvid * 128 + 2 * c2);
                    if (mm << 16) atomicMax(addr, (int)(mm << 16));
                    if (mm & 0xffff0000u) atomicMax(addr + 1, (int)(mm & 0xffff0000u));
                }
                pvid = vid; mm = 0;
            }
            u32 u = *(const u32*)&hbuf[r * 136 + 2 * c2];
            mm = pmax(mm, u);
        }
        if (pvid >= 0) {
            int* addr = (int*)(voxmax + (size_t)pvid * 128 + 2 * c2);
            if (mm << 16) atomicMax(addr, (int)(mm << 16));
            if (mm & 0xffff0000u) atomicMax(addr + 1, (int)(mm & 0xffff0000u));
        }
    }
}

// ---- generic MFMA GEMM: out = relu(A @ W + bias); A fp32 or bf16; W pre-swizzled bf16 ----
template<int K, int N, bool ABF16, bool OUT_BF16>
__global__ __launch_bounds__(256) void k_gemm_relu(
    const void* __restrict__ Ap, const u16* __restrict__ Wf,
    const float* __restrict__ bias, void* __restrict__ outp, int M)
{
    constexpr int STRIDE = K + 8;
    constexpr int TN = N / 64;
    constexpr int KSTEPS = K / 32;
    constexpr int CW = K / 4;
    __shared__ u16 lds[64 * STRIDE];
    int i0 = blockIdx.x * 64;
    int mcnt = M - i0; if (mcnt > 64) mcnt = 64;
    int t = threadIdx.x;
    {
        int row = t >> 2, cseg = t & 3;
        u16* dst = &lds[row * STRIDE + cseg * CW];
        if (row < mcnt) {
            if (ABF16) {
                const u16* src = (const u16*)Ap + (size_t)(i0 + row) * K + cseg * CW;
                #pragma unroll
                for (int c = 0; c < CW / 8; c++)
                    *(uintx4*)(dst + c * 8) = *(const uintx4*)(src + c * 8);
            } else {
                const float* src = (const float*)Ap + (size_t)(i0 + row) * K + cseg * CW;
                #pragma unroll
                for (int c = 0; c < CW / 8; c++) {
                    float4 v0 = *(const float4*)(src + c * 8);
                    float4 v1 = *(const float4*)(src + c * 8 + 4);
                    uintx4 rr = (uintx4){ pkbf(v0.x, v0.y), pkbf(v0.z, v0.w),
                                          pkbf(v1.x, v1.y), pkbf(v1.z, v1.w) };
                    *(uintx4*)(dst + c * 8) = rr;
                }
            }
        } else {
            short8 z = {0, 0, 0, 0, 0, 0, 0, 0};
            #pragma unroll
            for (int c = 0; c < CW / 8; c++) *(short8*)(dst + c * 8) = z;
        }
    }
    __syncthreads();
    int wave = t >> 6, l = t & 63;
    int q = l >> 4, lm = l & 15;
    int wn0 = wave * (N / 4);
    floatx4 acc[4][TN];
    #pragma unroll
    for (int a = 0; a < 4; a++)
        #pragma unroll
        for (int b = 0; b < TN; b++) acc[a][b] = (floatx4){0.f, 0.f, 0.f, 0.f};
    #pragma unroll
    for (int kk = 0; kk < KSTEPS; kk++) {
        short8 afrag[4], bfrag[TN];
        #pragma unroll
        for (int tm = 0; tm < 4; tm++)
            afrag[tm] = *(const short8*)&lds[(tm * 16 + lm) * STRIDE + kk * 32 + q * 8];
        #pragma unroll
        for (int tn = 0; tn < TN; tn++)
            bfrag[tn] = *(const short8*)&Wf[(size_t)((kk * 4 + q) * N + wn0 + tn * 16 + lm) * 8];
        #pragma unroll
        for (int tm = 0; tm < 4; tm++)
            #pragma unroll
            for (int tn = 0; tn < TN; tn++)
                acc[tm][tn] = __builtin_amdgcn_mfma_f32_16x16x32_bf16(afrag[tm], bfrag[tn], acc[tm][tn], 0, 0, 0);
    }
    #pragma unroll
    for (int tm = 0; tm < 4; tm++)
        #pragma unroll
        for (int tn = 0; tn < TN; tn++) {
            int n = wn0 + tn * 16 + lm;
            float bv = bias[n];
            #pragma unroll
            for (int r = 0; r < 4; r++) {
                int m = tm * 16 + q * 4 + r;
                if (m < mcnt) {
                    float v = fmaxf(acc[tm][tn][r] + bv, 0.f);
                    if (OUT_BF16) ((u16*)outp)[(size_t)(i0 + m) * N + n] = f2bf(v);
                    else          ((float*)outp)[(size_t)(i0 + m) * N + n] = v;
                }
            }
        }
}

// ---- K3: sorted fused point MLP + in-LDS segmented max -> vox2 ----
// Best-measured config (R10): 128-row x 256-col tile, 512 thr / 8 waves, LDS 67.6KB ->
// 2 blocks/CU. Wave owns a 32-col stripe, acc[2][8], ONE live bfrag. R11's 4x2 wave
// decomposition (shared col-groups) doubled per-block weight L2 traffic -> +45% dur;
// per-wave-tile operand traffic is set by tile shape, and distinct col ownership keeps
// each weight byte read once per block.
__global__ __launch_bounds__(512) void k_pointmlp(
    const u16* __restrict__ voxf, const u16* __restrict__ pf2s, const int* __restrict__ svid,
    const u16* __restrict__ w3f, const float* __restrict__ b3,
    const u16* __restrict__ w4f, const float* __restrict__ b4,
    float* __restrict__ vox2)
{
    constexpr int STRIDE = 264;
    __shared__ u16 lds[128 * STRIDE];   // 67.6 KB
    __shared__ int lvid[128];
    __shared__ float bl[512];   // b3(256) | b4(256)
    int i0 = blockIdx.x * 128;
    int mcnt = NPTS - i0; if (mcnt > 128) mcnt = 128;
    int t = threadIdx.x;
    if (t < 128) lvid[t] = (t < mcnt) ? svid[i0 + t] : -1;
    bl[t] = (t < 256) ? b3[t] : b4[t - 256];
    {   // stage: 4 threads/row; thread j covers u16 cols [j*32,+32) of each 128-col half
        int row = t >> 2, j = t & 3;
        int sv = (row < mcnt) ? svid[i0 + row] : 0;
        u16* dstb = &lds[row * STRIDE + j * 32];
        uintx4 v0 = (uintx4){0,0,0,0}, v1 = v0, v2 = v0, v3 = v0;
        uintx4 p0 = v0, p1 = v0, p2 = v0, p3 = v0;
        if (row < mcnt) {
            const u16* s0 = voxf + (size_t)sv * 128 + j * 32;            // pg half (sorted: locality)
            const u16* s1 = pf2s + (size_t)(i0 + row) * 128 + j * 32;    // pf2 half (coalesced)
            v0 = *(const uintx4*)s0;        v1 = *(const uintx4*)(s0 + 8);
            v2 = *(const uintx4*)(s0 + 16); v3 = *(const uintx4*)(s0 + 24);
            p0 = *(const uintx4*)s1;        p1 = *(const uintx4*)(s1 + 8);
            p2 = *(const uintx4*)(s1 + 16); p3 = *(const uintx4*)(s1 + 24);
        }
        *(uintx4*)(dstb)       = v0; *(uintx4*)(dstb + 8)   = v1;
        *(uintx4*)(dstb + 16)  = v2; *(uintx4*)(dstb + 24)  = v3;
        *(uintx4*)(dstb + 128) = p0; *(uintx4*)(dstb + 136) = p1;
        *(uintx4*)(dstb + 144) = p2; *(uintx4*)(dstb + 152) = p3;
    }
    __syncthreads();
    int wave = t >> 6, l = t & 63;
    int q = l >> 4, lm = l & 15;
    int wm0 = wave * 32;     // wave's 32-wide output-column stripe (8 waves x 32 = 256)
    floatx4 acc[2][8];
    #pragma unroll
    for (int a = 0; a < 2; a++)
        #pragma unroll
        for (int b = 0; b < 8; b++) acc[a][b] = (floatx4){0.f, 0.f, 0.f, 0.f};
    // GEMM1: D = W3^T @ Act^T over 128 rows (tn 0..7)
    #pragma unroll
    for (int kk = 0; kk < 8; kk++) {
        short8 wfrag[2];
        #pragma unroll
        for (int tm = 0; tm < 2; tm++)
            wfrag[tm] = *(const short8*)&w3f[(size_t)((kk * 4 + q) * 256 + wm0 + tm * 16 + lm) * 8];
        #pragma unroll
        for (int tn = 0; tn < 8; tn++) {
            short8 bfrag = *(const short8*)&lds[(tn * 16 + lm) * STRIDE + kk * 32 + q * 8];
            #pragma unroll
            for (int tm = 0; tm < 2; tm++)
                acc[tm][tn] = __builtin_amdgcn_mfma_f32_16x16x32_bf16(wfrag[tm], bfrag, acc[tm][tn], 0, 0, 0);
        }
    }
    __syncthreads();
    // H = relu(acc + b3) -> LDS row-major, packed b64 (4 consecutive cols per frag)
    #pragma unroll
    for (int tm = 0; tm < 2; tm++) {
        float4 bq = *(const float4*)&bl[wm0 + tm * 16 + 4 * q];
        #pragma unroll
        for (int tn = 0; tn < 8; tn++) {
            u32 lo = pkbf(fmaxf(acc[tm][tn][0] + bq.x, 0.f), fmaxf(acc[tm][tn][1] + bq.y, 0.f));
            u32 hi = pkbf(fmaxf(acc[tm][tn][2] + bq.z, 0.f), fmaxf(acc[tm][tn][3] + bq.w, 0.f));
            *(uintx2*)&lds[(tn * 16 + lm) * STRIDE + wm0 + tm * 16 + 4 * q] = (uintx2){lo, hi};
        }
    }
    __syncthreads();
    floatx4 acc2[2][8];
    #pragma unroll
    for (int a = 0; a < 2; a++)
        #pragma unroll
        for (int b = 0; b < 8; b++) acc2[a][b] = (floatx4){0.f, 0.f, 0.f, 0.f};
    // GEMM2: D = W4^T @ H^T
    #pragma unroll
    for (int kk = 0; kk < 8; kk++) {
        short8 wfrag[2];
        #pragma unroll
        for (int tm = 0; tm < 2; tm++)
            wfrag[tm] = *(const short8*)&w4f[(size_t)((kk * 4 + q) * 256 + wm0 + tm * 16 + lm) * 8];
        #pragma unroll
        for (int tn = 0; tn < 8; tn++) {
            short8 bfrag = *(const short8*)&lds[(tn * 16 + lm) * STRIDE + kk * 32 + q * 8];
            #pragma unroll
            for (int tm = 0; tm < 2; tm++)
                acc2[tm][tn] = __builtin_amdgcn_mfma_f32_16x16x32_bf16(wfrag[tm], bfrag, acc2[tm][tn], 0, 0, 0);
        }
    }
    __syncthreads();   // all waves done reading H before overwrite
    // pf5 = relu(acc2 + b4) -> LDS row-major, packed b64
    #pragma unroll
    for (int tm = 0; tm < 2; tm++) {
        float4 bq = *(const float4*)&bl[256 + wm0 + tm * 16 + 4 * q];
        #pragma unroll
        for (int tn = 0; tn < 8; tn++) {
            u32 lo = pkbf(fmaxf(acc2[tm][tn][0] + bq.x, 0.f), fmaxf(acc2[tm][tn][1] + bq.y, 0.f));
            u32 hi = pkbf(fmaxf(acc2[tm][tn][2] + bq.z, 0.f), fmaxf(acc2[tm][tn][3] + bq.w, 0.f));
            *(uintx2*)&lds[(tn * 16 + lm) * STRIDE + wm0 + tm * 16 + 4 * q] = (uintx2){lo, hi};
        }
    }
    __syncthreads();
    // segmented max over sorted vid runs: thread owns u32 col x 32-row strip
    {
        int c2 = t & 127;          // u32 column (u16 cols 2c2, 2c2+1)
        int h = t >> 7;            // row strip (32 rows)
        int r0 = h * 32;
        int r1 = r0 + 32; if (r1 > mcnt) r1 = mcnt;
        u32 mm = 0;
        int pvid = -1;
        for (int r = r0; r < r1; r++) {
            int vid = lvid[r];
            if (vid != pvid) {
                if (pvid >= 0) {
                    int* addr = (int*)(vox2 + (size_t)pvid * 256 + 2 * c2);
                    if (mm << 16) atomicMax(addr, (int)(mm << 16));
                    if (mm & 0xffff0000u) atomicMax(addr + 1, (int)(mm & 0xffff0000u));
                }
                pvid = vid; mm = 0;
            }
            u32 u = *(const u32*)&lds[r * STRIDE + 2 * c2];
            mm = pmax(mm, u);
        }
        if (pvid >= 0) {
            int* addr = (int*)(vox2 + (size_t)pvid * 256 + 2 * c2);
            if (mm << 16) atomicMax(addr, (int)(mm << 16));
            if (mm & 0xffff0000u) atomicMax(addr + 1, (int)(mm & 0xffff0000u));
        }
    }
}

extern "C" void kernel_launch(void* const* d_in, const int* in_sizes, int n_in,
                              void* d_out, int out_size, void* d_ws, size_t ws_size,
                              hipStream_t stream) {
    const float* inp = (const float*)d_in[0];
    const int*   idx = (const int*)d_in[1];
    const float* w1x = (const float*)d_in[3];  const float* b1x = (const float*)d_in[4];
    const float* w2x = (const float*)d_in[5];  const float* b2x = (const float*)d_in[6];
    const float* w1r = (const float*)d_in[7];  const float* b1r = (const float*)d_in[8];
    const float* w2r = (const float*)d_in[9];  const float* b2r = (const float*)d_in[10];
    const float* wax = (const float*)d_in[11]; const float* bax = (const float*)d_in[12];
    const float* war = (const float*)d_in[13]; const float* bar = (const float*)d_in[14];
    const float* wv1 = (const float*)d_in[15]; const float* bv1 = (const float*)d_in[16];
    const float* w3  = (const float*)d_in[17]; const float* b3  = (const float*)d_in[18];
    const float* w4  = (const float*)d_in[19]; const float* b4  = (const float*)d_in[20];
    const float* wv2 = (const float*)d_in[21]; const float* bv2 = (const float*)d_in[22];
    float* out = (float*)d_out;

    char* ws = (char*)d_ws;
    u16*   pf2s   = (u16*)ws;   ws += (size_t)NPTS * 128 * sizeof(u16);   // 128 MB (sorted rows)
    float* voxmax = (float*)ws; ws += (size_t)NVOX * 128 * sizeof(float); // 25.6 MB
    u16*   voxf   = (u16*)ws;   ws += (size_t)NVOX * 128 * sizeof(u16);   // 12.8 MB
    float* vox2   = (float*)ws; ws += (size_t)NVOX * 256 * sizeof(float); // 51.2 MB
    float* inps   = (float*)ws; ws += (size_t)NPTS * 6 * sizeof(float);   // 12 MB (sorted inp)
    u16*   w3f    = (u16*)ws;   ws += 65536 * sizeof(u16);
    u16*   w4f    = (u16*)ws;   ws += 65536 * sizeof(u16);
    u16*   wv1f   = (u16*)ws;   ws += 16384 * sizeof(u16);
    u16*   wv2f   = (u16*)ws;   ws += 65536 * sizeof(u16);
    u16*   wcatf  = (u16*)ws;   ws += 8192 * sizeof(u16);
    u16*   wattf  = (u16*)ws;   ws += 4096 * sizeof(u16);
    int*   hcnt   = (int*)ws;   ws += (size_t)NVOX * sizeof(int);
    int*   cur    = (int*)ws;   ws += (size_t)NVOX * sizeof(int);
    int*   bsum   = (int*)ws;   ws += (size_t)NBLK * sizeof(int);
    int*   boff   = (int*)ws;   ws += (size_t)NBLK * sizeof(int);
    int*   svid   = (int*)ws;   ws += (size_t)NPTS * sizeof(int);

    hipMemsetAsync(voxmax, 0, (size_t)NVOX * 128 * sizeof(float), stream);
    hipMemsetAsync(vox2, 0, (size_t)NVOX * 256 * sizeof(float), stream);

    k_prep<<<1076, 256, 0, stream>>>(w3, w3f, w4, w4f, wv1, wv1f, wv2, wv2f,
                                     w2x, w2r, wcatf, wax, war, wattf, hcnt);

    k_hist<<<(NPTS + 255) / 256, 256, 0, stream>>>(idx, hcnt);
    k_scan1<<<NBLK, 256, 0, stream>>>(hcnt, bsum);
    k_scan2<<<1, 256, 0, stream>>>(bsum, boff);
    k_scan3<<<NBLK, 256, 0, stream>>>(hcnt, boff, cur);
    k_scatter<<<(NPTS + 255) / 256, 256, 0, stream>>>(idx, cur, inp, inps, svid);

    k_pointfeat<<<(NPTS + 63) / 64, 512, 0, stream>>>(
        inps, svid, w1x, b1x, w1r, b1r, wcatf, b2x, b2r, wattf, bax, bar, pf2s, voxmax);

    k_gemm_relu<128, 128, false, true><<<(NVOX + 63) / 64, 256, 0, stream>>>(
        (const void*)voxmax, wv1f, bv1, (void*)voxf, NVOX);

    k_pointmlp<<<(NPTS + 127) / 128, 512, 0, stream>>>(
        voxf, pf2s, svid, w3f, b3, w4f, b4, vox2);

    k_gemm_relu<256, 256, false, false><<<(NVOX + 63) / 64, 256, 0, stream>>>(
        (const void*)vox2, wv2f, bv2, (void*)out, NVOX);
}

// Round 13
// 471.197 us; speedup vs baseline: 1.1641x; 1.0208x over previous
//
#include <hip/hip_runtime.h>

#define NPTS 500000
#define NVOX 50000
#define NBLK 196   // ceil(NVOX/256)

typedef unsigned short u16;
typedef unsigned int u32;
typedef __attribute__((ext_vector_type(8))) short short8;
typedef __attribute__((ext_vector_type(4))) float floatx4;
typedef __attribute__((ext_vector_type(4))) unsigned int uintx4;
typedef __attribute__((ext_vector_type(2))) unsigned int uintx2;
typedef __attribute__((ext_vector_type(2))) unsigned short us2;

// packed fp32->bf16 RNE (1 instr for 2 values)
__device__ __forceinline__ u32 pkbf(float lo, float hi) {
    u32 r;
    asm("v_cvt_pk_bf16_f32 %0, %1, %2" : "=v"(r) : "v"(lo), "v"(hi));
    return r;
}
__device__ __forceinline__ u16 f2bf(float f) {
    u32 r;
    asm("v_cvt_pk_bf16_f32 %0, %1, %1" : "=v"(r) : "v"(f));
    return (u16)r;
}
// packed u16 max (bf16 values >= 0 compare as u16)
__device__ __forceinline__ u32 pmax(u32 a, u32 b) {
    us2 r = __builtin_elementwise_max(__builtin_bit_cast(us2, a), __builtin_bit_cast(us2, b));
    return __builtin_bit_cast(u32, r);
}

// ---- weight swizzle helper: fp32 (K x N row-major) -> fragment-contiguous bf16 ----
//   Wf[((kk*4+q)*N + n)*8 + j] = W[(kk*32+q*8+j)*N + n]
__device__ __forceinline__ void wt_one(const float* __restrict__ W, u16* __restrict__ Wf,
                                       int N, int t, int KN) {
    if (t >= KN) return;
    int k = t / N, n = t - k * N;
    int kk = k >> 5, q = (k >> 3) & 3, j = k & 7;
    Wf[((size_t)((kk * 4 + q) * N + n) << 3) + j] = f2bf(W[t]);
}

// ---- K0: output-buffer zeroing + ALL weight transforms + hcnt zero in ONE launch ----
// (R13: memsets folded in — 2 fewer dispatch boundaries, zeroing overlaps transforms)
// blocks [0,6250) voxmax=0 | [6250,18750) vox2=0 | [18750,19006) w3 | [19006,19262) w4 |
// [19262,19326) wv1 | [19326,19582) wv2 | [19582,19614) wcat | [19614,19630) watt |
// [19630,19826) hcnt=0
__global__ __launch_bounds__(256) void k_prep(
    float* __restrict__ voxmax, float* __restrict__ vox2,
    const float* __restrict__ w3, u16* __restrict__ w3f,
    const float* __restrict__ w4, u16* __restrict__ w4f,
    const float* __restrict__ wv1, u16* __restrict__ wv1f,
    const float* __restrict__ wv2, u16* __restrict__ wv2f,
    const float* __restrict__ w2x, const float* __restrict__ w2r, u16* __restrict__ wcatf,
    const float* __restrict__ wax, const float* __restrict__ war, u16* __restrict__ wattf,
    int* __restrict__ hcnt)
{
    int b = blockIdx.x, tid = threadIdx.x;
    if (b < 6250) {              // zero voxmax: 6250*256*16B = 25.6 MB
        ((uintx4*)voxmax)[(size_t)b * 256 + tid] = (uintx4){0, 0, 0, 0};
    } else if (b < 18750) {      // zero vox2: 12500*256*16B = 51.2 MB
        ((uintx4*)vox2)[(size_t)(b - 6250) * 256 + tid] = (uintx4){0, 0, 0, 0};
    } else if (b < 19006) {
        wt_one(w3, w3f, 256, (b - 18750) * 256 + tid, 65536);
    } else if (b < 19262) {
        wt_one(w4, w4f, 256, (b - 19006) * 256 + tid, 65536);
    } else if (b < 19326) {
        wt_one(wv1, wv1f, 128, (b - 19262) * 256 + tid, 16384);
    } else if (b < 19582) {
        wt_one(wv2, wv2f, 256, (b - 19326) * 256 + tid, 65536);
    } else if (b < 19614) {      // block-diag [[w2x,0],[0,w2r]] (128x64)
        int t = (b - 19582) * 256 + tid;
        int k = t >> 6, n = t & 63;
        float v;
        if (k < 64) v = (n < 32) ? w2x[k * 32 + n] : 0.f;
        else        v = (n >= 32) ? w2r[(k - 64) * 32 + (n - 32)] : 0.f;
        int kk = k >> 5, q = (k >> 3) & 3, j = k & 7;
        wcatf[((size_t)((kk * 4 + q) * 64 + n) << 3) + j] = f2bf(v);
    } else if (b < 19630) {      // [wax | war] (64x64)
        int t = (b - 19614) * 256 + tid;
        int k = t >> 6, n = t & 63;
        float v = (n < 32) ? wax[k * 32 + n] : war[k * 32 + (n - 32)];
        int kk = k >> 5, q = (k >> 3) & 3, j = k & 7;
        wattf[((size_t)((kk * 4 + q) * 64 + n) << 3) + j] = f2bf(v);
    } else {                     // zero hcnt
        int i = (b - 19630) * 256 + tid;
        if (i < NVOX) hcnt[i] = 0;
    }
}

// ---- CSR build: histogram -> 3-phase parallel scan -> scatter (inps permute + sorted vid) ----
__global__ void k_hist(const int* __restrict__ idx, int* __restrict__ hcnt) {
    int i = blockIdx.x * 256 + threadIdx.x;
    if (i < NPTS) atomicAdd(&hcnt[idx[i]], 1);
}

__global__ __launch_bounds__(256) void k_scan1(const int* __restrict__ hcnt, int* __restrict__ bsum) {
    __shared__ int wsum[4];
    int t = threadIdx.x;
    int i = blockIdx.x * 256 + t;
    int c = (i < NVOX) ? hcnt[i] : 0;
    #pragma unroll
    for (int d = 32; d >= 1; d >>= 1) c += __shfl_xor(c, d, 64);
    if ((t & 63) == 0) wsum[t >> 6] = c;
    __syncthreads();
    if (t == 0) bsum[blockIdx.x] = wsum[0] + wsum[1] + wsum[2] + wsum[3];
}

__global__ __launch_bounds__(256) void k_scan2(const int* __restrict__ bsum, int* __restrict__ boff) {
    __shared__ int wsum[4];
    int t = threadIdx.x, lane = t & 63, w = t >> 6;
    int c = (t < NBLK) ? bsum[t] : 0;
    int v = c;
    #pragma unroll
    for (int d = 1; d < 64; d <<= 1) {
        int o = __shfl_up(v, d, 64);
        if (lane >= d) v += o;
    }
    if (lane == 63) wsum[w] = v;
    __syncthreads();
    int wo = 0;
    #pragma unroll
    for (int k = 0; k < 4; k++) if (k < w) wo += wsum[k];
    if (t < NBLK) boff[t] = wo + v - c;
}

__global__ __launch_bounds__(256) void k_scan3(const int* __restrict__ hcnt, const int* __restrict__ boff,
                                               int* __restrict__ cur) {
    __shared__ int wsum[4];
    int t = threadIdx.x, lane = t & 63, w = t >> 6;
    int i = blockIdx.x * 256 + t;
    int c = (i < NVOX) ? hcnt[i] : 0;
    int v = c;
    #pragma unroll
    for (int d = 1; d < 64; d <<= 1) {
        int o = __shfl_up(v, d, 64);
        if (lane >= d) v += o;
    }
    if (lane == 63) wsum[w] = v;
    __syncthreads();
    int wo = 0;
    #pragma unroll
    for (int k = 0; k < 4; k++) if (k < w) wo += wsum[k];
    if (i < NVOX) cur[i] = boff[blockIdx.x] + wo + v - c;
}

// scatter: permute inp rows into sorted order (random access lives HERE, where
// scattered WRITES don't stall waves; k_pointfeat then reads inps fully coalesced)
__global__ void k_scatter(const int* __restrict__ idx, int* __restrict__ cur,
                          const float* __restrict__ inp,
                          float* __restrict__ inps, int* __restrict__ svid) {
    int i = blockIdx.x * 256 + threadIdx.x;
    if (i < NPTS) {
        int v = idx[i];
        int pos = atomicAdd(&cur[v], 1);
        svid[pos] = v;
        const float2* s = (const float2*)(inp + (size_t)i * 6);
        float2 a = s[0], b = s[1], c = s[2];
        float2* d = (float2*)(inps + (size_t)pos * 6);
        d[0] = a; d[1] = b; d[2] = c;
    }
}

// ---- K1: sorted-order MFMA point encoder + fused pf2 segment-max -> voxmax (fp32) ----
// 512 threads / 8 waves; inps read coalesced; segmax 4x16-row groups on 256 lanes.
__global__ __launch_bounds__(512) void k_pointfeat(
    const float* __restrict__ inps, const int* __restrict__ svid,
    const float* __restrict__ w1x, const float* __restrict__ b1x,
    const float* __restrict__ w1r, const float* __restrict__ b1r,
    const u16* __restrict__ wcatf, const float* __restrict__ b2x, const float* __restrict__ b2r,
    const u16* __restrict__ wattf, const float* __restrict__ bax, const float* __restrict__ bar,
    u16* __restrict__ pf2s, float* __restrict__ voxmax)
{
    __shared__ u16 hbuf[64 * 136];   // h tile (64x128 +8 pad); reused for pf2 out-tile
    __shared__ u16 cbuf[64 * 72];    // comb tile (64x64 +8 pad)
    __shared__ float wl[512];        // w1x(192) b1x(64) w1r(192) b1r(64)
    __shared__ int lvid[64];
    int t = threadIdx.x;
    int i0 = blockIdx.x * 64;
    int mcnt = NPTS - i0; if (mcnt > 64) mcnt = 64;
    {
        float v;
        if (t < 192)      v = w1x[t];
        else if (t < 256) v = b1x[t - 192];
        else if (t < 448) v = w1r[t - 256];
        else              v = b1r[t - 448];
        wl[t] = v;
    }
    if (t < 64) lvid[t] = (t < mcnt) ? svid[i0 + t] : -1;
    __syncthreads();
    {   // layer 1: K=3 on VALU, 8 threads/point each produce 8 h_x + 8 h_r cols
        int m = t >> 3, c = t & 7;
        float x0 = 0, x1 = 0, x2 = 0, r0 = 0, r1 = 0, r2 = 0;
        if (m < mcnt) {
            const float* p = inps + (size_t)(i0 + m) * 6;   // sorted, coalesced
            x0 = p[0]; x1 = p[1]; x2 = p[2]; r0 = p[3]; r1 = p[4]; r2 = p[5];
        }
        u16* hb = &hbuf[m * 136 + c * 8];
        #pragma unroll
        for (int jp = 0; jp < 4; jp++) {
            int c0 = c * 8 + 2 * jp, c1 = c0 + 1;
            float hx0 = fmaxf(wl[192 + c0] + x0 * wl[c0] + x1 * wl[64 + c0] + x2 * wl[128 + c0], 0.f);
            float hx1 = fmaxf(wl[192 + c1] + x0 * wl[c1] + x1 * wl[64 + c1] + x2 * wl[128 + c1], 0.f);
            float hr0 = fmaxf(wl[448 + c0] + r0 * wl[256 + c0] + r1 * wl[320 + c0] + r2 * wl[384 + c0], 0.f);
            float hr1 = fmaxf(wl[448 + c1] + r0 * wl[256 + c1] + r1 * wl[320 + c1] + r2 * wl[384 + c1], 0.f);
            *(u32*)(hb + 2 * jp)      = pkbf(hx0, hx1);
            *(u32*)(hb + 64 + 2 * jp) = pkbf(hr0, hr1);
        }
    }
    __syncthreads();
    int wave = t >> 6, l = t & 63, q = l >> 4, lm = l & 15;
    int g = wave & 3;          // col group: n = g*16+lm
    int h2 = wave >> 2;        // row half: tm in {2h2, 2h2+1}
    int n = g * 16 + lm;
    // GEMM1: comb(64x64) = h(64x128) @ wcat(128x64); wave does 2 of 4 row-tiles
    floatx4 acc[2];
    #pragma unroll
    for (int a = 0; a < 2; a++) acc[a] = (floatx4){0.f, 0.f, 0.f, 0.f};
    #pragma unroll
    for (int kk = 0; kk < 4; kk++) {
        short8 bfrag = *(const short8*)&wcatf[(size_t)((kk * 4 + q) * 64 + n) << 3];
        #pragma unroll
        for (int ti = 0; ti < 2; ti++) {
            int tm = h2 * 2 + ti;
            short8 afrag = *(const short8*)&hbuf[(tm * 16 + lm) * 136 + kk * 32 + q * 8];
            acc[ti] = __builtin_amdgcn_mfma_f32_16x16x32_bf16(afrag, bfrag, acc[ti], 0, 0, 0);
        }
    }
    float bv = (n < 32) ? b2x[n] : b2r[n - 32];
    float comb_keep[2][4];
    #pragma unroll
    for (int ti = 0; ti < 2; ti++)
        #pragma unroll
        for (int r = 0; r < 4; r++) {
            int tm = h2 * 2 + ti;
            float v = fmaxf(acc[ti][r] + bv, 0.f);
            comb_keep[ti][r] = v;
            int m = tm * 16 + q * 4 + r;     // C/D: row = quad*4+reg, col = lane&15
            cbuf[m * 72 + n] = f2bf(v);
        }
    __syncthreads();
    // GEMM2: att(64x64) = comb @ watt; same C-layout as comb -> register-local gating
    floatx4 acc2[2];
    #pragma unroll
    for (int a = 0; a < 2; a++) acc2[a] = (floatx4){0.f, 0.f, 0.f, 0.f};
    #pragma unroll
    for (int kk = 0; kk < 2; kk++) {
        short8 bfrag = *(const short8*)&wattf[(size_t)((kk * 4 + q) * 64 + n) << 3];
        #pragma unroll
        for (int ti = 0; ti < 2; ti++) {
            int tm = h2 * 2 + ti;
            short8 afrag = *(const short8*)&cbuf[(tm * 16 + lm) * 72 + kk * 32 + q * 8];
            acc2[ti] = __builtin_amdgcn_mfma_f32_16x16x32_bf16(afrag, bfrag, acc2[ti], 0, 0, 0);
        }
    }
    float bv2 = (n < 32) ? bax[n] : bar[n - 32];
    int pp = (n < 32) ? n : 32 + n;   // pf2 col of plain value; gated at pp+32
    #pragma unroll
    for (int ti = 0; ti < 2; ti++)
        #pragma unroll
        for (int r = 0; r < 4; r++) {
            int tm = h2 * 2 + ti;
            float att = acc2[ti][r] + bv2;
            float sg = 1.f / (1.f + __expf(-att));
            float plain = comb_keep[ti][r];
            float gated = plain * sg;
            int m = tm * 16 + q * 4 + r;
            hbuf[m * 136 + pp] = f2bf(plain);
            hbuf[m * 136 + pp + 32] = f2bf(gated);
        }
    __syncthreads();
    {   // coalesced pf2s store (sorted rows): 8 threads/row x 16B
        int row = t >> 3, seg = t & 7;
        if (row < mcnt) {
            const u16* src = &hbuf[row * 136 + seg * 16];
            u16* dst = pf2s + (size_t)(i0 + row) * 128 + seg * 16;
            *(uintx4*)dst = *(const uintx4*)src;
        }
    }
    if (t < 256) {   // fused segment-max: 4x16-row groups, 256 lanes
        int c2 = t & 63;           // u32 col (u16 cols 2c2, 2c2+1) of 128
        int h = t >> 6;            // row quarter (16 rows)
        int r0 = h * 16;
        int r1 = r0 + 16; if (r1 > mcnt) r1 = mcnt;
        u32 mm = 0;
        int pvid = -1;
        for (int r = r0; r < r1; r++) {
            int vid = lvid[r];
            if (vid != pvid) {
                if (pvid >= 0) {
                    int* addr = (int*)(voxmax + (size_t)pvid * 128 + 2 * c2);
                    if (mm << 16) atomicMax(addr, (int)(mm << 16));
                    if (mm & 0xffff0000u) atomicMax(addr + 1, (int)(mm & 0xffff0000u));
                }
                pvid = vid; mm = 0;
            }
            u32 u = *(const u32*)&hbuf[r * 136 + 2 * c2];
            mm = pmax(mm, u);
        }
        if (pvid >= 0) {
            int* addr = (int*)(voxmax + (size_t)pvid * 128 + 2 * c2);
            if (mm << 16) atomicMax(addr, (int)(mm << 16));
            if (mm & 0xffff0000u) atomicMax(addr + 1, (int)(mm & 0xffff0000u));
        }
    }
}

// ---- generic MFMA GEMM: out = relu(A @ W + bias); A fp32 or bf16; W pre-swizzled bf16 ----
template<int K, int N, bool ABF16, bool OUT_BF16>
__global__ __launch_bounds__(256) void k_gemm_relu(
    const void* __restrict__ Ap, const u16* __restrict__ Wf,
    const float* __restrict__ bias, void* __restrict__ outp, int M)
{
    constexpr int STRIDE = K + 8;
    constexpr int TN = N / 64;
    constexpr int KSTEPS = K / 32;
    constexpr int CW = K / 4;
    __shared__ u16 lds[64 * STRIDE];
    int i0 = blockIdx.x * 64;
    int mcnt = M - i0; if (mcnt > 64) mcnt = 64;
    int t = threadIdx.x;
    {
        int row = t >> 2, cseg = t & 3;
        u16* dst = &lds[row * STRIDE + cseg * CW];
        if (row < mcnt) {
            if (ABF16) {
                const u16* src = (const u16*)Ap + (size_t)(i0 + row) * K + cseg * CW;
                #pragma unroll
                for (int c = 0; c < CW / 8; c++)
                    *(uintx4*)(dst + c * 8) = *(const uintx4*)(src + c * 8);
            } else {
                const float* src = (const float*)Ap + (size_t)(i0 + row) * K + cseg * CW;
                #pragma unroll
                for (int c = 0; c < CW / 8; c++) {
                    float4 v0 = *(const float4*)(src + c * 8);
                    float4 v1 = *(const float4*)(src + c * 8 + 4);
                    uintx4 rr = (uintx4){ pkbf(v0.x, v0.y), pkbf(v0.z, v0.w),
                                          pkbf(v1.x, v1.y), pkbf(v1.z, v1.w) };
                    *(uintx4*)(dst + c * 8) = rr;
                }
            }
        } else {
            short8 z = {0, 0, 0, 0, 0, 0, 0, 0};
            #pragma unroll
            for (int c = 0; c < CW / 8; c++) *(short8*)(dst + c * 8) = z;
        }
    }
    __syncthreads();
    int wave = t >> 6, l = t & 63;
    int q = l >> 4, lm = l & 15;
    int wn0 = wave * (N / 4);
    floatx4 acc[4][TN];
    #pragma unroll
    for (int a = 0; a < 4; a++)
        #pragma unroll
        for (int b = 0; b < TN; b++) acc[a][b] = (floatx4){0.f, 0.f, 0.f, 0.f};
    #pragma unroll
    for (int kk = 0; kk < KSTEPS; kk++) {
        short8 afrag[4], bfrag[TN];
        #pragma unroll
        for (int tm = 0; tm < 4; tm++)
            afrag[tm] = *(const short8*)&lds[(tm * 16 + lm) * STRIDE + kk * 32 + q * 8];
        #pragma unroll
        for (int tn = 0; tn < TN; tn++)
            bfrag[tn] = *(const short8*)&Wf[(size_t)((kk * 4 + q) * N + wn0 + tn * 16 + lm) * 8];
        #pragma unroll
        for (int tm = 0; tm < 4; tm++)
            #pragma unroll
            for (int tn = 0; tn < TN; tn++)
                acc[tm][tn] = __builtin_amdgcn_mfma_f32_16x16x32_bf16(afrag[tm], bfrag[tn], acc[tm][tn], 0, 0, 0);
    }
    #pragma unroll
    for (int tm = 0; tm < 4; tm++)
        #pragma unroll
        for (int tn = 0; tn < TN; tn++) {
            int n = wn0 + tn * 16 + lm;
            float bv = bias[n];
            #pragma unroll
            for (int r = 0; r < 4; r++) {
                int m = tm * 16 + q * 4 + r;
                if (m < mcnt) {
                    float v = fmaxf(acc[tm][tn][r] + bv, 0.f);
                    if (OUT_BF16) ((u16*)outp)[(size_t)(i0 + m) * N + n] = f2bf(v);
                    else          ((float*)outp)[(size_t)(i0 + m) * N + n] = v;
                }
            }
        }
}

// ---- K3: sorted fused point MLP + in-LDS segmented max -> vox2 ----
// Best-measured config (R10/R12): 128-row x 256-col tile, 512 thr / 8 waves, LDS 67.6KB
// -> 2 blocks/CU. Wave owns a 32-col stripe, acc[2][8], ONE live bfrag. R11 lesson:
// distinct col ownership per wave is mandatory (each weight byte read once per block).
__global__ __launch_bounds__(512) void k_pointmlp(
    const u16* __restrict__ voxf, const u16* __restrict__ pf2s, const int* __restrict__ svid,
    const u16* __restrict__ w3f, const float* __restrict__ b3,
    const u16* __restrict__ w4f, const float* __restrict__ b4,
    float* __restrict__ vox2)
{
    constexpr int STRIDE = 264;
    __shared__ u16 lds[128 * STRIDE];   // 67.6 KB
    __shared__ int lvid[128];
    __shared__ float bl[512];   // b3(256) | b4(256)
    int i0 = blockIdx.x * 128;
    int mcnt = NPTS - i0; if (mcnt > 128) mcnt = 128;
    int t = threadIdx.x;
    if (t < 128) lvid[t] = (t < mcnt) ? svid[i0 + t] : -1;
    bl[t] = (t < 256) ? b3[t] : b4[t - 256];
    {   // stage: 4 threads/row; thread j covers u16 cols [j*32,+32) of each 128-col half
        int row = t >> 2, j = t & 3;
        int sv = (row < mcnt) ? svid[i0 + row] : 0;
        u16* dstb = &lds[row * STRIDE + j * 32];
        uintx4 v0 = (uintx4){0,0,0,0}, v1 = v0, v2 = v0, v3 = v0;
        uintx4 p0 = v0, p1 = v0, p2 = v0, p3 = v0;
        if (row < mcnt) {
            const u16* s0 = voxf + (size_t)sv * 128 + j * 32;            // pg half (sorted: locality)
            const u16* s1 = pf2s + (size_t)(i0 + row) * 128 + j * 32;    // pf2 half (coalesced)
            v0 = *(const uintx4*)s0;        v1 = *(const uintx4*)(s0 + 8);
            v2 = *(const uintx4*)(s0 + 16); v3 = *(const uintx4*)(s0 + 24);
            p0 = *(const uintx4*)s1;        p1 = *(const uintx4*)(s1 + 8);
            p2 = *(const uintx4*)(s1 + 16); p3 = *(const uintx4*)(s1 + 24);
        }
        *(uintx4*)(dstb)       = v0; *(uintx4*)(dstb + 8)   = v1;
        *(uintx4*)(dstb + 16)  = v2; *(uintx4*)(dstb + 24)  = v3;
        *(uintx4*)(dstb + 128) = p0; *(uintx4*)(dstb + 136) = p1;
        *(uintx4*)(dstb + 144) = p2; *(uintx4*)(dstb + 152) = p3;
    }
    __syncthreads();
    int wave = t >> 6, l = t & 63;
    int q = l >> 4, lm = l & 15;
    int wm0 = wave * 32;     // wave's 32-wide output-column stripe (8 waves x 32 = 256)
    floatx4 acc[2][8];
    #pragma unroll
    for (int a = 0; a < 2; a++)
        #pragma unroll
        for (int b = 0; b < 8; b++) acc[a][b] = (floatx4){0.f, 0.f, 0.f, 0.f};
    // GEMM1: D = W3^T @ Act^T over 128 rows (tn 0..7)
    #pragma unroll
    for (int kk = 0; kk < 8; kk++) {
        short8 wfrag[2];
        #pragma unroll
        for (int tm = 0; tm < 2; tm++)
            wfrag[tm] = *(const short8*)&w3f[(size_t)((kk * 4 + q) * 256 + wm0 + tm * 16 + lm) * 8];
        #pragma unroll
        for (int tn = 0; tn < 8; tn++) {
            short8 bfrag = *(const short8*)&lds[(tn * 16 + lm) * STRIDE + kk * 32 + q * 8];
            #pragma unroll
            for (int tm = 0; tm < 2; tm++)
                acc[tm][tn] = __builtin_amdgcn_mfma_f32_16x16x32_bf16(wfrag[tm], bfrag, acc[tm][tn], 0, 0, 0);
        }
    }
    __syncthreads();
    // H = relu(acc + b3) -> LDS row-major, packed b64 (4 consecutive cols per frag)
    #pragma unroll
    for (int tm = 0; tm < 2; tm++) {
        float4 bq = *(const float4*)&bl[wm0 + tm * 16 + 4 * q];
        #pragma unroll
        for (int tn = 0; tn < 8; tn++) {
            u32 lo = pkbf(fmaxf(acc[tm][tn][0] + bq.x, 0.f), fmaxf(acc[tm][tn][1] + bq.y, 0.f));
            u32 hi = pkbf(fmaxf(acc[tm][tn][2] + bq.z, 0.f), fmaxf(acc[tm][tn][3] + bq.w, 0.f));
            *(uintx2*)&lds[(tn * 16 + lm) * STRIDE + wm0 + tm * 16 + 4 * q] = (uintx2){lo, hi};
        }
    }
    __syncthreads();
    floatx4 acc2[2][8];
    #pragma unroll
    for (int a = 0; a < 2; a++)
        #pragma unroll
        for (int b = 0; b < 8; b++) acc2[a][b] = (floatx4){0.f, 0.f, 0.f, 0.f};
    // GEMM2: D = W4^T @ H^T
    #pragma unroll
    for (int kk = 0; kk < 8; kk++) {
        short8 wfrag[2];
        #pragma unroll
        for (int tm = 0; tm < 2; tm++)
            wfrag[tm] = *(const short8*)&w4f[(size_t)((kk * 4 + q) * 256 + wm0 + tm * 16 + lm) * 8];
        #pragma unroll
        for (int tn = 0; tn < 8; tn++) {
            short8 bfrag = *(const short8*)&lds[(tn * 16 + lm) * STRIDE + kk * 32 + q * 8];
            #pragma unroll
            for (int tm = 0; tm < 2; tm++)
                acc2[tm][tn] = __builtin_amdgcn_mfma_f32_16x16x32_bf16(wfrag[tm], bfrag, acc2[tm][tn], 0, 0, 0);
        }
    }
    __syncthreads();   // all waves done reading H before overwrite
    // pf5 = relu(acc2 + b4) -> LDS row-major, packed b64
    #pragma unroll
    for (int tm = 0; tm < 2; tm++) {
        float4 bq = *(const float4*)&bl[256 + wm0 + tm * 16 + 4 * q];
        #pragma unroll
        for (int tn = 0; tn < 8; tn++) {
            u32 lo = pkbf(fmaxf(acc2[tm][tn][0] + bq.x, 0.f), fmaxf(acc2[tm][tn][1] + bq.y, 0.f));
            u32 hi = pkbf(fmaxf(acc2[tm][tn][2] + bq.z, 0.f), fmaxf(acc2[tm][tn][3] + bq.w, 0.f));
            *(uintx2*)&lds[(tn * 16 + lm) * STRIDE + wm0 + tm * 16 + 4 * q] = (uintx2){lo, hi};
        }
    }
    __syncthreads();
    // segmented max over sorted vid runs: thread owns u32 col x 32-row strip
    {
        int c2 = t & 127;          // u32 column (u16 cols 2c2, 2c2+1)
        int h = t >> 7;            // row strip (32 rows)
        int r0 = h * 32;
        int r1 = r0 + 32; if (r1 > mcnt) r1 = mcnt;
        u32 mm = 0;
        int pvid = -1;
        for (int r = r0; r < r1; r++) {
            int vid = lvid[r];
            if (vid != pvid) {
                if (pvid >= 0) {
                    int* addr = (int*)(vox2 + (size_t)pvid * 256 + 2 * c2);
                    if (mm << 16) atomicMax(addr, (int)(mm << 16));
                    if (mm & 0xffff0000u) atomicMax(addr + 1, (int)(mm & 0xffff0000u));
                }
                pvid = vid; mm = 0;
            }
            u32 u = *(const u32*)&lds[r * STRIDE + 2 * c2];
            mm = pmax(mm, u);
        }
        if (pvid >= 0) {
            int* addr = (int*)(vox2 + (size_t)pvid * 256 + 2 * c2);
            if (mm << 16) atomicMax(addr, (int)(mm << 16));
            if (mm & 0xffff0000u) atomicMax(addr + 1, (int)(mm & 0xffff0000u));
        }
    }
}

extern "C" void kernel_launch(void* const* d_in, const int* in_sizes, int n_in,
                              void* d_out, int out_size, void* d_ws, size_t ws_size,
                              hipStream_t stream) {
    const float* inp = (const float*)d_in[0];
    const int*   idx = (const int*)d_in[1];
    const float* w1x = (const float*)d_in[3];  const float* b1x = (const float*)d_in[4];
    const float* w2x = (const float*)d_in[5];  const float* b2x = (const float*)d_in[6];
    const float* w1r = (const float*)d_in[7];  const float* b1r = (const float*)d_in[8];
    const float* w2r = (const float*)d_in[9];  const float* b2r = (const float*)d_in[10];
    const float* wax = (const float*)d_in[11]; const float* bax = (const float*)d_in[12];
    const float* war = (const float*)d_in[13]; const float* bar = (const float*)d_in[14];
    const float* wv1 = (const float*)d_in[15]; const float* bv1 = (const float*)d_in[16];
    const float* w3  = (const float*)d_in[17]; const float* b3  = (const float*)d_in[18];
    const float* w4  = (const float*)d_in[19]; const float* b4  = (const float*)d_in[20];
    const float* wv2 = (const float*)d_in[21]; const float* bv2 = (const float*)d_in[22];
    float* out = (float*)d_out;

    char* ws = (char*)d_ws;
    u16*   pf2s   = (u16*)ws;   ws += (size_t)NPTS * 128 * sizeof(u16);   // 128 MB (sorted rows)
    float* voxmax = (float*)ws; ws += (size_t)NVOX * 128 * sizeof(float); // 25.6 MB
    u16*   voxf   = (u16*)ws;   ws += (size_t)NVOX * 128 * sizeof(u16);   // 12.8 MB
    float* vox2   = (float*)ws; ws += (size_t)NVOX * 256 * sizeof(float); // 51.2 MB
    float* inps   = (float*)ws; ws += (size_t)NPTS * 6 * sizeof(float);   // 12 MB (sorted inp)
    u16*   w3f    = (u16*)ws;   ws += 65536 * sizeof(u16);
    u16*   w4f    = (u16*)ws;   ws += 65536 * sizeof(u16);
    u16*   wv1f   = (u16*)ws;   ws += 16384 * sizeof(u16);
    u16*   wv2f   = (u16*)ws;   ws += 65536 * sizeof(u16);
    u16*   wcatf  = (u16*)ws;   ws += 8192 * sizeof(u16);
    u16*   wattf  = (u16*)ws;   ws += 4096 * sizeof(u16);
    int*   hcnt   = (int*)ws;   ws += (size_t)NVOX * sizeof(int);
    int*   cur    = (int*)ws;   ws += (size_t)NVOX * sizeof(int);
    int*   bsum   = (int*)ws;   ws += (size_t)NBLK * sizeof(int);
    int*   boff   = (int*)ws;   ws += (size_t)NBLK * sizeof(int);
    int*   svid   = (int*)ws;   ws += (size_t)NPTS * sizeof(int);

    k_prep<<<19826, 256, 0, stream>>>(voxmax, vox2,
                                      w3, w3f, w4, w4f, wv1, wv1f, wv2, wv2f,
                                      w2x, w2r, wcatf, wax, war, wattf, hcnt);

    k_hist<<<(NPTS + 255) / 256, 256, 0, stream>>>(idx, hcnt);
    k_scan1<<<NBLK, 256, 0, stream>>>(hcnt, bsum);
    k_scan2<<<1, 256, 0, stream>>>(bsum, boff);
    k_scan3<<<NBLK, 256, 0, stream>>>(hcnt, boff, cur);
    k_scatter<<<(NPTS + 255) / 256, 256, 0, stream>>>(idx, cur, inp, inps, svid);

    k_pointfeat<<<(NPTS + 63) / 64, 512, 0, stream>>>(
        inps, svid, w1x, b1x, w1r, b1r, wcatf, b2x, b2r, wattf, bax, bar, pf2s, voxmax);

    k_gemm_relu<128, 128, false, true><<<(NVOX + 63) / 64, 256, 0, stream>>>(
        (const void*)voxmax, wv1f, bv1, (void*)voxf, NVOX);

    k_pointmlp<<<(NPTS + 127) / 128, 512, 0, stream>>>(
        voxf, pf2s, svid, w3f, b3, w4f, b4, vox2);

    k_gemm_relu<256, 256, false, false><<<(NVOX + 63) / 64, 256, 0, stream>>>(
        (const void*)vox2, wv2f, bv2, (void*)out, NVOX);
}